// Round 9
// baseline (227.856 us; speedup 1.0000x reference)
//
#include <hip/hip_runtime.h>
#include <cstdint>
#include <math.h>

// ---------- types ----------
typedef __attribute__((ext_vector_type(8))) short bf16x8;   // MFMA A/B operand (4 VGPRs)
typedef __attribute__((ext_vector_type(4))) float f32x4;    // MFMA C/D operand
typedef __attribute__((ext_vector_type(4))) unsigned short u16x4;

__device__ __forceinline__ unsigned short f2bf(float f) {
  union { float f; unsigned int u; } c; c.f = f;
  unsigned int u = c.u;
  return (unsigned short)((u + 0x7FFFu + ((u >> 16) & 1u)) >> 16);  // RNE
}

// pack hi16(a) | hi16(b)<<16 via v_perm_b32 (1 VALU op; trunc-to-bf16)
__device__ __forceinline__ unsigned int pack_trunc(float a, float b) {
  return __builtin_amdgcn_perm(__float_as_uint(b), __float_as_uint(a), 0x07060302u);
}

__device__ __forceinline__ float fmax3(float a, float b, float c) {
  return fmaxf(fmaxf(a, b), c);  // clang fuses to v_max3_f32
}

__device__ __forceinline__ void gload_lds16(const void* g, void* l) {
  __builtin_amdgcn_global_load_lds(
      (const __attribute__((address_space(1))) unsigned int*)g,
      (__attribute__((address_space(3))) unsigned int*)l, 16, 0, 0);
}

// ---------- fp32 -> bf16 convert (vectorized) ----------
__global__ __launch_bounds__(256)
void k_convert(const float* __restrict__ in, unsigned short* __restrict__ out, int n4) {
  int i = blockIdx.x * 256 + threadIdx.x;
  if (i >= n4) return;
  float4 v = ((const float4*)in)[i];
  u16x4 o;
  o.x = f2bf(v.x); o.y = f2bf(v.y); o.z = f2bf(v.z); o.w = f2bf(v.w);
  ((u16x4*)out)[i] = o;
}

// ---------- fp32 [R][C] -> bf16 [C][R] transpose ----------
__global__ __launch_bounds__(256)
void k_transpose_conv(const float* __restrict__ in, unsigned short* __restrict__ out,
                      int R, int C) {
  __shared__ float t[32][33];
  int c0 = blockIdx.x * 32, r0 = blockIdx.y * 32;
  int tx = threadIdx.x & 31, ty = threadIdx.x >> 5;  // 32 x 8
#pragma unroll
  for (int rr = ty; rr < 32; rr += 8) t[rr][tx] = in[(size_t)(r0 + rr) * C + c0 + tx];
  __syncthreads();
#pragma unroll
  for (int cc = ty; cc < 32; cc += 8)
    out[(size_t)(c0 + cc) * R + r0 + tx] = f2bf(t[tx][cc]);
}

// ---------- bf16 GEMM 128x128, dbuf + 1 barrier/K-step (T3-min) ----------
template <int OUTBF>
__global__ __launch_bounds__(256)
void k_gemm_bt(const unsigned short* __restrict__ A, const unsigned short* __restrict__ BT,
               void* __restrict__ C, int M, int N, int K) {
  __shared__ __align__(16) unsigned short As[2][128 * 32];
  __shared__ __align__(16) unsigned short Bs[2][128 * 32];
  const int tid = threadIdx.x;
  const int wid = tid >> 6, lane = tid & 63;
  const int l16 = lane & 15, krow = lane >> 4;
  const int m0 = blockIdx.x * 128, n0 = blockIdx.y * 128;
  const int wr = wid >> 1, wc = wid & 1;  // 2x2 waves, 64x64 each

  f32x4 acc[4][4] = {};

  auto stageG = [&](int buf, int k0) {
#pragma unroll
    for (int j = 0; j < 2; j++) {
      int f = j * 256 + tid;
      gload_lds16(A  + (size_t)(m0 + (f >> 2)) * K + k0 + (f & 3) * 8,
                  (char*)As[buf] + (size_t)(j * 256 + wid * 64) * 16);
      gload_lds16(BT + (size_t)(n0 + (f >> 2)) * K + k0 + (f & 3) * 8,
                  (char*)Bs[buf] + (size_t)(j * 256 + wid * 64) * 16);
    }
  };
  auto comp = [&](int buf) {
    bf16x8 a[4], b[4];
#pragma unroll
    for (int i = 0; i < 4; i++) {
      a[i] = *(const bf16x8*)&As[buf][(wr * 64 + i * 16 + l16) * 32 + krow * 8];
      b[i] = *(const bf16x8*)&Bs[buf][(wc * 64 + i * 16 + l16) * 32 + krow * 8];
    }
#pragma unroll
    for (int mi = 0; mi < 4; mi++)
#pragma unroll
      for (int ni = 0; ni < 4; ni++)
        acc[mi][ni] = __builtin_amdgcn_mfma_f32_16x16x32_bf16(a[mi], b[ni], acc[mi][ni], 0, 0, 0);
  };

  stageG(0, 0);
  __syncthreads();
  for (int k0 = 0; k0 < K; k0 += 64) {
    if (k0 + 32 < K) stageG(1, k0 + 32);
    comp(0);
    __syncthreads();
    if (k0 + 64 < K) stageG(0, k0 + 64);
    comp(1);
    __syncthreads();
  }

#pragma unroll
  for (int mi = 0; mi < 4; mi++)
#pragma unroll
    for (int ni = 0; ni < 4; ni++)
#pragma unroll
      for (int r = 0; r < 4; r++) {
        int row = m0 + wr * 64 + mi * 16 + krow * 4 + r;
        int col = n0 + wc * 64 + ni * 16 + l16;
        float v = acc[mi][ni][r];
        if (OUTBF) ((unsigned short*)C)[(size_t)row * N + col] = f2bf(v);
        else       ((float*)C)[(size_t)row * N + col] = v;
      }
}

// ---------- bf16 GEMM 128x64, dbuf + 1 barrier/K-step ----------
template <int OUTBF>
__global__ __launch_bounds__(256)
void k_gemm_bt_n64(const unsigned short* __restrict__ A, const unsigned short* __restrict__ BT,
                   void* __restrict__ C, int M, int N, int K) {
  __shared__ __align__(16) unsigned short As[2][128 * 32];
  __shared__ __align__(16) unsigned short Bs[2][64 * 32];
  const int tid = threadIdx.x;
  const int wid = tid >> 6, lane = tid & 63;
  const int l16 = lane & 15, krow = lane >> 4;
  const int m0 = blockIdx.x * 128, n0 = blockIdx.y * 64;
  const int wr = wid >> 1, wc = wid & 1;  // 2x2 waves, 64x32 each

  f32x4 acc[4][2] = {};

  auto stageG = [&](int buf, int k0) {
#pragma unroll
    for (int j = 0; j < 2; j++) {
      int f = j * 256 + tid;
      gload_lds16(A + (size_t)(m0 + (f >> 2)) * K + k0 + (f & 3) * 8,
                  (char*)As[buf] + (size_t)(j * 256 + wid * 64) * 16);
    }
    gload_lds16(BT + (size_t)(n0 + (tid >> 2)) * K + k0 + (tid & 3) * 8,
                (char*)Bs[buf] + (size_t)(wid * 64) * 16);
  };
  auto comp = [&](int buf) {
    bf16x8 a[4], b[2];
#pragma unroll
    for (int i = 0; i < 4; i++)
      a[i] = *(const bf16x8*)&As[buf][(wr * 64 + i * 16 + l16) * 32 + krow * 8];
#pragma unroll
    for (int i = 0; i < 2; i++)
      b[i] = *(const bf16x8*)&Bs[buf][(wc * 32 + i * 16 + l16) * 32 + krow * 8];
#pragma unroll
    for (int mi = 0; mi < 4; mi++)
#pragma unroll
      for (int ni = 0; ni < 2; ni++)
        acc[mi][ni] = __builtin_amdgcn_mfma_f32_16x16x32_bf16(a[mi], b[ni], acc[mi][ni], 0, 0, 0);
  };

  stageG(0, 0);
  __syncthreads();
  for (int k0 = 0; k0 < K; k0 += 64) {
    if (k0 + 32 < K) stageG(1, k0 + 32);
    comp(0);
    __syncthreads();
    if (k0 + 64 < K) stageG(0, k0 + 64);
    comp(1);
    __syncthreads();
  }

#pragma unroll
  for (int mi = 0; mi < 4; mi++)
#pragma unroll
    for (int ni = 0; ni < 2; ni++)
#pragma unroll
      for (int r = 0; r < 4; r++) {
        int row = m0 + wr * 64 + mi * 16 + krow * 4 + r;
        int col = n0 + wc * 32 + ni * 16 + l16;
        float v = acc[mi][ni][r];
        if (OUTBF) ((unsigned short*)C)[(size_t)row * N + col] = f2bf(v);
        else       ((float*)C)[(size_t)row * N + col] = v;
      }
}

// ---------- V transpose (tiled): Vt[h*64+d][s] = QKV[s][2048 + h*64 + d] ----------
__global__ __launch_bounds__(256)
void k_vt(const unsigned short* __restrict__ QKV, unsigned short* __restrict__ Vt) {
  __shared__ unsigned short t[64 * 65];
  const int tid = threadIdx.x;
  const int s0 = blockIdx.x * 64, c0 = blockIdx.y * 64;
  const int sl = tid >> 3, ch = tid & 7;  // 32 rows x 8 chunks per pass
#pragma unroll
  for (int half = 0; half < 2; half++) {
    int s = half * 32 + sl;
    bf16x8 v = *(const bf16x8*)&QKV[(size_t)(s0 + s) * 3072 + 2048 + c0 + ch * 8];
#pragma unroll
    for (int k = 0; k < 8; k++) t[s * 65 + ch * 8 + k] = (unsigned short)v[k];
  }
  __syncthreads();
  const int cl = tid >> 2, si = (tid & 3) * 16;
  bf16x8 o0, o1;
#pragma unroll
  for (int i = 0; i < 8; i++) o0[i] = (short)t[(si + i) * 65 + cl];
#pragma unroll
  for (int i = 0; i < 8; i++) o1[i] = (short)t[(si + 8 + i) * 65 + cl];
  *(bf16x8*)&Vt[(size_t)(c0 + cl) * 4096 + s0 + si] = o0;
  *(bf16x8*)&Vt[(size_t)(c0 + cl) * 4096 + s0 + si + 8] = o1;
}

// ---------- flash attention ----------
// 4 waves/WG, 16 q-rows/WAVE (64 q-rows/WG), grid 1024 (16 heads x 64 qb),
// LDS 32 KB -> 4 WG/CU = 16 waves/CU (2x prior occupancy). KV tiles of 64,
// dbuf K+V staging. Swapped QK^T -> lane-local softmax with per-lane partial
// max (cross-lane reduce only on defer-max trigger) and per-lane partial l
// (reduced once in epilogue). PV: P^T B-frag = lane's own packed sacc under
// k-slot perm pi; V A-frag = two ds_read_b64 under the same pi.
__global__ __launch_bounds__(256)
void k_flash(const unsigned short* __restrict__ QKV, const unsigned short* __restrict__ Vt,
             unsigned short* __restrict__ ctx) {
  // shorts: dbuf 2 x (K 4096 | V 4096) = 32 KB
  __shared__ __align__(16) unsigned short LDS[16384];
  const int tid = threadIdx.x, wid = tid >> 6, lane = tid & 63;
  const int l16 = lane & 15, krow = lane >> 4;
  const int bid = blockIdx.x;
  const int swz = (bid & 7) * 128 + (bid >> 3);   // 1024 % 8 == 0 -> bijective
  const int head = swz >> 6, qb = swz & 63;       // 2 heads per XCD (K/V/Q ~3MB < 4MB L2)
  const float SC = 0.125f * 1.44269504089f;       // scale into log2 domain

  // Q fragments (B-operand of swapped QK^T): lane holds q-row l16, d = ks*32+krow*8..+7
  bf16x8 qf[2];
#pragma unroll
  for (int ks = 0; ks < 2; ks++) {
    int row = qb * 64 + wid * 16 + l16;
    qf[ks] = *(const bf16x8*)&QKV[(size_t)row * 3072 + head * 64 + ks * 32 + krow * 8];
  }

  f32x4 oaccT[4] = {};      // O^T tiles [di]; col=q(l16), row=d(krow*4+r)
  float mrun = -INFINITY;   // uniform across the 4 krow-lanes of a q
  float lrun = 0.f;         // PER-LANE partial (reduced in epilogue)

  auto stage = [&](int buf, int kt) {
#pragma unroll
    for (int j = 0; j < 2; j++) {
      int f = j * 256 + tid, row = f >> 3, sch = (f & 7) ^ (row & 7);  // pre-swizzled source
      gload_lds16(QKV + (size_t)(kt * 64 + row) * 3072 + 1024 + head * 64 + sch * 8,
                  (char*)LDS + buf * 16384 + (j * 256 + wid * 64) * 16);
      gload_lds16(Vt + (size_t)(head * 64 + row) * 4096 + kt * 64 + sch * 8,
                  (char*)LDS + buf * 16384 + 8192 + (j * 256 + wid * 64) * 16);
    }
  };

  auto body = [&](int buf) {
    const unsigned short* Ks = LDS + buf * 8192;
    const char* VsB = (const char*)(LDS + buf * 8192 + 4096);

    // swapped QK^T: sacc[ni] = S^T tile [kv 16][q 16]; lane owns q=l16, kv=ni*16+krow*4+r
    f32x4 sacc[4] = {};
    __builtin_amdgcn_s_setprio(1);
#pragma unroll
    for (int ks = 0; ks < 2; ks++)
#pragma unroll
      for (int ni = 0; ni < 4; ni++) {
        int row = ni * 16 + l16;
        bf16x8 kf = *(const bf16x8*)&Ks[row * 64 + (((ks * 4 + krow) ^ (row & 7)) << 3)];
        sacc[ni] = __builtin_amdgcn_mfma_f32_16x16x32_bf16(kf, qf[ks], sacc[ni], 0, 0, 0);
      }
    __builtin_amdgcn_s_setprio(0);

    // per-lane partial max over this lane's 16 kv values (raw domain)
    float a = fmax3(sacc[0][0], sacc[0][1], sacc[0][2]);
    a = fmax3(a, sacc[0][3], sacc[1][0]);
    a = fmax3(a, sacc[1][1], sacc[1][2]);
    a = fmax3(a, sacc[1][3], sacc[2][0]);
    a = fmax3(a, sacc[2][1], sacc[2][2]);
    a = fmax3(a, sacc[2][3], sacc[3][0]);
    a = fmax3(a, sacc[3][1], sacc[3][2]);
    a = fmaxf(a, sacc[3][3]);

    // defer-max: cross-lane reduce + rescale only when some lane's partial
    // exceeds the running max by > 8 (log2 domain)
    if (__ballot(__builtin_fmaf(a, SC, -mrun) > 8.f)) {
      a = fmaxf(a, __shfl_xor(a, 16));
      a = fmaxf(a, __shfl_xor(a, 32));      // uniform per q now
      float mnew = fmaxf(mrun, a * SC);
      float al = __builtin_amdgcn_exp2f(mrun - mnew);
      lrun *= al;
      mrun = mnew;
#pragma unroll
      for (int di = 0; di < 4; di++)
#pragma unroll
        for (int r = 0; r < 4; r++) oaccT[di][r] *= al;
    }

    // P = exp2(s*SC - m); per-lane partial row-sum
#pragma unroll
    for (int ni = 0; ni < 4; ni++)
#pragma unroll
      for (int r = 0; r < 4; r++) {
        float p = __builtin_amdgcn_exp2f(__builtin_fmaf(sacc[ni][r], SC, -mrun));
        sacc[ni][r] = p;
        lrun += p;
      }

    // B-frags: P^T packed from this lane's OWN sacc under k-slot perm pi:
    //   pi(ks,krow,j) = (2ks + (j>>2))*16 + krow*4 + (j&3)
    union PB { unsigned int w[4]; bf16x8 v; };
    PB pb[2];
#pragma unroll
    for (int ks = 0; ks < 2; ks++) {
      pb[ks].w[0] = pack_trunc(sacc[2 * ks][0],     sacc[2 * ks][1]);
      pb[ks].w[1] = pack_trunc(sacc[2 * ks][2],     sacc[2 * ks][3]);
      pb[ks].w[2] = pack_trunc(sacc[2 * ks + 1][0], sacc[2 * ks + 1][1]);
      pb[ks].w[3] = pack_trunc(sacc[2 * ks + 1][2], sacc[2 * ks + 1][3]);
    }

    // O^T += V^T P^T: A-frag under same pi = two b64 reads from swizzled Vs
    __builtin_amdgcn_s_setprio(1);
#pragma unroll
    for (int ks = 0; ks < 2; ks++)
#pragma unroll
      for (int di = 0; di < 4; di++) {
        int row = di * 16 + l16;
        int base = row * 128 + ((krow & 1) << 3);
        union PB av;
        *(uint2*)&av.w[0] = *(const uint2*)(VsB + base + (((ks * 4 + (krow >> 1)) ^ (row & 7)) << 4));
        *(uint2*)&av.w[2] = *(const uint2*)(VsB + base + (((ks * 4 + 2 + (krow >> 1)) ^ (row & 7)) << 4));
        oaccT[di] = __builtin_amdgcn_mfma_f32_16x16x32_bf16(av.v, pb[ks].v, oaccT[di], 0, 0, 0);
      }
    __builtin_amdgcn_s_setprio(0);
  };

  stage(0, 0);
  __syncthreads();
  for (int kt = 0; kt < 64; kt += 2) {
    stage(1, kt + 1);
    body(0);
    __syncthreads();           // buf1 staged+drained; all reads of buf0 done
    if (kt + 2 < 64) stage(0, kt + 2);
    body(1);
    __syncthreads();
  }

  // epilogue: reduce per-lane l partials across the 4 krow-lanes of each q,
  // then per-lane normalize + 8B packed stores
  float lr = lrun;
  lr += __shfl_xor(lr, 16);
  lr += __shfl_xor(lr, 32);
  float li = 1.0f / lr;
  int row = qb * 64 + wid * 16 + l16;
#pragma unroll
  for (int di = 0; di < 4; di++) {
    uint2 w;
    w.x = (unsigned)f2bf(oaccT[di][0] * li) | ((unsigned)f2bf(oaccT[di][1] * li) << 16);
    w.y = (unsigned)f2bf(oaccT[di][2] * li) | ((unsigned)f2bf(oaccT[di][3] * li) << 16);
    *(uint2*)&ctx[(size_t)row * 1024 + head * 64 + di * 16 + krow * 4] = w;
  }
}

// ---------- LN(base + add): emits fp32 + bf16 copies ----------
__global__ __launch_bounds__(256)
void k_ln_res(const float* __restrict__ base, const float* __restrict__ add,
              const float* __restrict__ g, const float* __restrict__ bb,
              float* __restrict__ outf, unsigned short* __restrict__ outb) {
  const int r = blockIdx.x, tid = threadIdx.x;
  float4 v = ((const float4*)(base + (size_t)r * 1024))[tid];
  {
    float4 w = ((const float4*)(add + (size_t)r * 1024))[tid];
    v.x += w.x; v.y += w.y; v.z += w.z; v.w += w.w;
  }
  float s1 = v.x + v.y + v.z + v.w;
  float s2 = v.x * v.x + v.y * v.y + v.z * v.z + v.w * v.w;
#pragma unroll
  for (int off = 32; off >= 1; off >>= 1) { s1 += __shfl_xor(s1, off); s2 += __shfl_xor(s2, off); }
  __shared__ float red[8];
  if ((tid & 63) == 0) { red[tid >> 6] = s1; red[4 + (tid >> 6)] = s2; }
  __syncthreads();
  s1 = red[0] + red[1] + red[2] + red[3];
  s2 = red[4] + red[5] + red[6] + red[7];
  const float mu = s1 * (1.0f / 1024.0f);
  const float var = s2 * (1.0f / 1024.0f) - mu * mu;
  const float rs = rsqrtf(var + 1e-5f);
  float4 gv = ((const float4*)g)[tid];
  float4 bv = ((const float4*)bb)[tid];
  float4 y;
  y.x = (v.x - mu) * rs * gv.x + bv.x;
  y.y = (v.y - mu) * rs * gv.y + bv.y;
  y.z = (v.z - mu) * rs * gv.z + bv.z;
  y.w = (v.w - mu) * rs * gv.w + bv.w;
  ((float4*)(outf + (size_t)r * 1024))[tid] = y;
  u16x4 o;
  o.x = f2bf(y.x); o.y = f2bf(y.y); o.z = f2bf(y.z); o.w = f2bf(y.w);
  ((u16x4*)(outb + (size_t)r * 1024))[tid] = o;
}

// ---------- relu(LN(lin + out_b + mha)) -> fp32 out ----------
__global__ __launch_bounds__(256)
void k_ln2(const float* __restrict__ lin, const float* __restrict__ mha,
           const float* __restrict__ ob, const float* __restrict__ g,
           const float* __restrict__ bb, float* __restrict__ out) {
  const int r = blockIdx.x, tid = threadIdx.x;
  float4 v = ((const float4*)(lin + (size_t)r * 1024))[tid];
  {
    float4 w = ((const float4*)(mha + (size_t)r * 1024))[tid];
    float4 o = ((const float4*)ob)[tid];
    v.x += w.x + o.x; v.y += w.y + o.y; v.z += w.z + o.z; v.w += w.w + o.w;
  }
  float s1 = v.x + v.y + v.z + v.w;
  float s2 = v.x * v.x + v.y * v.y + v.z * v.z + v.w * v.w;
#pragma unroll
  for (int off = 32; off >= 1; off >>= 1) { s1 += __shfl_xor(s1, off); s2 += __shfl_xor(s2, off); }
  __shared__ float red[8];
  if ((tid & 63) == 0) { red[tid >> 6] = s1; red[4 + (tid >> 6)] = s2; }
  __syncthreads();
  s1 = red[0] + red[1] + red[2] + red[3];
  s2 = red[4] + red[5] + red[6] + red[7];
  const float mu = s1 * (1.0f / 1024.0f);
  const float var = s2 * (1.0f / 1024.0f) - mu * mu;
  const float rs = rsqrtf(var + 1e-5f);
  float4 gv = ((const float4*)g)[tid];
  float4 bv = ((const float4*)bb)[tid];
  float4 y;
  y.x = fmaxf(0.f, (v.x - mu) * rs * gv.x + bv.x);
  y.y = fmaxf(0.f, (v.y - mu) * rs * gv.y + bv.y);
  y.z = fmaxf(0.f, (v.z - mu) * rs * gv.z + bv.z);
  y.w = fmaxf(0.f, (v.w - mu) * rs * gv.w + bv.w);
  ((float4*)(out + (size_t)r * 1024))[tid] = y;
}

// ---------- launch ----------
extern "C" void kernel_launch(void* const* d_in, const int* in_sizes, int n_in,
                              void* d_out, int out_size, void* d_ws, size_t ws_size,
                              hipStream_t stream) {
  (void)in_sizes; (void)n_in; (void)out_size; (void)ws_size;
  const float* x     = (const float*)d_in[0];
  const float* Wq    = (const float*)d_in[1];
  const float* Wk    = (const float*)d_in[2];
  const float* Wv    = (const float*)d_in[3];
  const float* Wo    = (const float*)d_in[4];
  const float* out_w = (const float*)d_in[5];
  const float* out_b = (const float*)d_in[6];
  const float* g1    = (const float*)d_in[7];
  const float* b1    = (const float*)d_in[8];
  const float* g2    = (const float*)d_in[9];
  const float* b2    = (const float*)d_in[10];
  float* out = (float*)d_out;

  // workspace layout (aliased; 60 MB total, liveness-checked)
  const size_t MB = 1ull << 20;
  char* ws = (char*)d_ws;
  unsigned short* xb    = (unsigned short*)(ws + 0);        // [4096][1024] bf16   (dead after GEMM1)
  unsigned short* WqkvT = (unsigned short*)(ws + 8 * MB);   // [3072][1024] bf16   (dead after GEMM1)
  unsigned short* OwB   = (unsigned short*)(ws + 16 * MB);  // out_w bf16 [1024][1024]
  unsigned short* QKV   = (unsigned short*)(ws + 18 * MB);  // [4096][3072] bf16   (dead after attn)
  unsigned short* Vt    = (unsigned short*)(ws + 42 * MB);  // [1024][4096] bf16   (dead after attn)
  unsigned short* ctx   = (unsigned short*)(ws + 50 * MB);  // [4096][1024] bf16   (dead after GEMM2)
  unsigned short* WoT   = (unsigned short*)(ws + 58 * MB);  // W_o^T bf16
  float*          proj  = (float*)(ws + 0);                 // [4096][1024] f32 (over xb/WqkvT)
  float*          mhaF  = (float*)(ws + 18 * MB);           // [4096][1024] f32 (over QKV head)
  unsigned short* mhaB  = (unsigned short*)(ws + 34 * MB);  // [4096][1024] bf16 (over QKV tail)
  float*          lin   = (float*)(ws + 42 * MB);           // [4096][1024] f32 (over Vt/ctx)

  k_convert<<<4096, 256, 0, stream>>>(x, xb, 1048576);
  k_convert<<<1024, 256, 0, stream>>>(out_w, OwB, 262144);
  k_transpose_conv<<<dim3(32, 32), 256, 0, stream>>>(Wq, WqkvT,                1024, 1024);
  k_transpose_conv<<<dim3(32, 32), 256, 0, stream>>>(Wk, WqkvT + 1024 * 1024,  1024, 1024);
  k_transpose_conv<<<dim3(32, 32), 256, 0, stream>>>(Wv, WqkvT + 2048 * 1024,  1024, 1024);
  k_transpose_conv<<<dim3(32, 32), 256, 0, stream>>>(Wo, WoT, 1024, 1024);

  k_gemm_bt<1><<<dim3(32, 24), 256, 0, stream>>>(xb, WqkvT, QKV, 4096, 3072, 1024);
  k_vt<<<dim3(64, 16), 256, 0, stream>>>(QKV, Vt);
  k_flash<<<1024, 256, 0, stream>>>(QKV, Vt, ctx);
  k_gemm_bt_n64<0><<<dim3(32, 16), 256, 0, stream>>>(ctx, WoT, proj, 4096, 1024, 1024);
  k_ln_res<<<4096, 256, 0, stream>>>(x, proj, g1, b1, mhaF, mhaB);
  k_gemm_bt_n64<0><<<dim3(32, 16), 256, 0, stream>>>(mhaB, OwB, lin, 4096, 1024, 1024);
  k_ln2<<<4096, 256, 0, stream>>>(lin, mhaF, out_b, g2, b2, out);
}

// Round 10
// 208.366 us; speedup vs baseline: 1.0935x; 1.0935x over previous
//
#include <hip/hip_runtime.h>
#include <cstdint>
#include <math.h>

// ---------- types ----------
typedef __attribute__((ext_vector_type(8))) short bf16x8;   // MFMA A/B operand (4 VGPRs)
typedef __attribute__((ext_vector_type(4))) float f32x4;    // MFMA C/D operand
typedef __attribute__((ext_vector_type(4))) unsigned short u16x4;

__device__ __forceinline__ unsigned short f2bf(float f) {
  union { float f; unsigned int u; } c; c.f = f;
  unsigned int u = c.u;
  return (unsigned short)((u + 0x7FFFu + ((u >> 16) & 1u)) >> 16);  // RNE
}

// pack hi16(a) | hi16(b)<<16 via v_perm_b32 (1 VALU op; trunc-to-bf16)
__device__ __forceinline__ unsigned int pack_trunc(float a, float b) {
  return __builtin_amdgcn_perm(__float_as_uint(b), __float_as_uint(a), 0x07060302u);
}

__device__ __forceinline__ float fmax3(float a, float b, float c) {
  return fmaxf(fmaxf(a, b), c);  // clang fuses to v_max3_f32
}

__device__ __forceinline__ void gload_lds16(const void* g, void* l) {
  __builtin_amdgcn_global_load_lds(
      (const __attribute__((address_space(1))) unsigned int*)g,
      (__attribute__((address_space(3))) unsigned int*)l, 16, 0, 0);
}

// ---------- fp32 -> bf16 convert (x and out_w in one launch) ----------
__global__ __launch_bounds__(256)
void k_convert2(const float* __restrict__ inA, unsigned short* __restrict__ outA,
                const float* __restrict__ inB, unsigned short* __restrict__ outB,
                int n4A, int n4B) {
  int i = blockIdx.x * 256 + threadIdx.x;
  if (i < n4A) {
    float4 v = ((const float4*)inA)[i];
    u16x4 o;
    o.x = f2bf(v.x); o.y = f2bf(v.y); o.z = f2bf(v.z); o.w = f2bf(v.w);
    ((u16x4*)outA)[i] = o;
  } else {
    int j = i - n4A;
    if (j >= n4B) return;
    float4 v = ((const float4*)inB)[j];
    u16x4 o;
    o.x = f2bf(v.x); o.y = f2bf(v.y); o.z = f2bf(v.z); o.w = f2bf(v.w);
    ((u16x4*)outB)[j] = o;
  }
}

// ---------- fp32 [1024][1024] -> bf16 [1024][1024] transpose, 4 matrices ----------
__global__ __launch_bounds__(256)
void k_transpose4(const float* __restrict__ w0, const float* __restrict__ w1,
                  const float* __restrict__ w2, const float* __restrict__ w3,
                  unsigned short* __restrict__ o012, unsigned short* __restrict__ o3) {
  __shared__ float t[32][33];
  const float* in = blockIdx.z == 0 ? w0 : blockIdx.z == 1 ? w1 : blockIdx.z == 2 ? w2 : w3;
  unsigned short* out = blockIdx.z < 3 ? o012 + (size_t)blockIdx.z * 1048576 : o3;
  int c0 = blockIdx.x * 32, r0 = blockIdx.y * 32;
  int tx = threadIdx.x & 31, ty = threadIdx.x >> 5;  // 32 x 8
#pragma unroll
  for (int rr = ty; rr < 32; rr += 8) t[rr][tx] = in[(size_t)(r0 + rr) * 1024 + c0 + tx];
  __syncthreads();
#pragma unroll
  for (int cc = ty; cc < 32; cc += 8)
    out[(size_t)(c0 + cc) * 1024 + r0 + tx] = f2bf(t[tx][cc]);
}

// ---------- bf16 GEMM 128x128, dbuf + 1 barrier/K-step (T3-min) ----------
template <int OUTBF>
__global__ __launch_bounds__(256)
void k_gemm_bt(const unsigned short* __restrict__ A, const unsigned short* __restrict__ BT,
               void* __restrict__ C, int M, int N, int K) {
  __shared__ __align__(16) unsigned short As[2][128 * 32];
  __shared__ __align__(16) unsigned short Bs[2][128 * 32];
  const int tid = threadIdx.x;
  const int wid = tid >> 6, lane = tid & 63;
  const int l16 = lane & 15, krow = lane >> 4;
  const int m0 = blockIdx.x * 128, n0 = blockIdx.y * 128;
  const int wr = wid >> 1, wc = wid & 1;  // 2x2 waves, 64x64 each

  f32x4 acc[4][4] = {};

  auto stageG = [&](int buf, int k0) {
#pragma unroll
    for (int j = 0; j < 2; j++) {
      int f = j * 256 + tid;
      gload_lds16(A  + (size_t)(m0 + (f >> 2)) * K + k0 + (f & 3) * 8,
                  (char*)As[buf] + (size_t)(j * 256 + wid * 64) * 16);
      gload_lds16(BT + (size_t)(n0 + (f >> 2)) * K + k0 + (f & 3) * 8,
                  (char*)Bs[buf] + (size_t)(j * 256 + wid * 64) * 16);
    }
  };
  auto comp = [&](int buf) {
    bf16x8 a[4], b[4];
#pragma unroll
    for (int i = 0; i < 4; i++) {
      a[i] = *(const bf16x8*)&As[buf][(wr * 64 + i * 16 + l16) * 32 + krow * 8];
      b[i] = *(const bf16x8*)&Bs[buf][(wc * 64 + i * 16 + l16) * 32 + krow * 8];
    }
#pragma unroll
    for (int mi = 0; mi < 4; mi++)
#pragma unroll
      for (int ni = 0; ni < 4; ni++)
        acc[mi][ni] = __builtin_amdgcn_mfma_f32_16x16x32_bf16(a[mi], b[ni], acc[mi][ni], 0, 0, 0);
  };

  stageG(0, 0);
  __syncthreads();
  for (int k0 = 0; k0 < K; k0 += 64) {
    if (k0 + 32 < K) stageG(1, k0 + 32);
    comp(0);
    __syncthreads();
    if (k0 + 64 < K) stageG(0, k0 + 64);
    comp(1);
    __syncthreads();
  }

#pragma unroll
  for (int mi = 0; mi < 4; mi++)
#pragma unroll
    for (int ni = 0; ni < 4; ni++)
#pragma unroll
      for (int r = 0; r < 4; r++) {
        int row = m0 + wr * 64 + mi * 16 + krow * 4 + r;
        int col = n0 + wc * 64 + ni * 16 + l16;
        float v = acc[mi][ni][r];
        if (OUTBF) ((unsigned short*)C)[(size_t)row * N + col] = f2bf(v);
        else       ((float*)C)[(size_t)row * N + col] = v;
      }
}

// ---------- bf16 GEMM 128x64, dbuf + 1 barrier/K-step ----------
template <int OUTBF>
__global__ __launch_bounds__(256)
void k_gemm_bt_n64(const unsigned short* __restrict__ A, const unsigned short* __restrict__ BT,
                   void* __restrict__ C, int M, int N, int K) {
  __shared__ __align__(16) unsigned short As[2][128 * 32];
  __shared__ __align__(16) unsigned short Bs[2][64 * 32];
  const int tid = threadIdx.x;
  const int wid = tid >> 6, lane = tid & 63;
  const int l16 = lane & 15, krow = lane >> 4;
  const int m0 = blockIdx.x * 128, n0 = blockIdx.y * 64;
  const int wr = wid >> 1, wc = wid & 1;  // 2x2 waves, 64x32 each

  f32x4 acc[4][2] = {};

  auto stageG = [&](int buf, int k0) {
#pragma unroll
    for (int j = 0; j < 2; j++) {
      int f = j * 256 + tid;
      gload_lds16(A + (size_t)(m0 + (f >> 2)) * K + k0 + (f & 3) * 8,
                  (char*)As[buf] + (size_t)(j * 256 + wid * 64) * 16);
    }
    gload_lds16(BT + (size_t)(n0 + (tid >> 2)) * K + k0 + (tid & 3) * 8,
                (char*)Bs[buf] + (size_t)(wid * 64) * 16);
  };
  auto comp = [&](int buf) {
    bf16x8 a[4], b[2];
#pragma unroll
    for (int i = 0; i < 4; i++)
      a[i] = *(const bf16x8*)&As[buf][(wr * 64 + i * 16 + l16) * 32 + krow * 8];
#pragma unroll
    for (int i = 0; i < 2; i++)
      b[i] = *(const bf16x8*)&Bs[buf][(wc * 32 + i * 16 + l16) * 32 + krow * 8];
#pragma unroll
    for (int mi = 0; mi < 4; mi++)
#pragma unroll
      for (int ni = 0; ni < 2; ni++)
        acc[mi][ni] = __builtin_amdgcn_mfma_f32_16x16x32_bf16(a[mi], b[ni], acc[mi][ni], 0, 0, 0);
  };

  stageG(0, 0);
  __syncthreads();
  for (int k0 = 0; k0 < K; k0 += 64) {
    if (k0 + 32 < K) stageG(1, k0 + 32);
    comp(0);
    __syncthreads();
    if (k0 + 64 < K) stageG(0, k0 + 64);
    comp(1);
    __syncthreads();
  }

#pragma unroll
  for (int mi = 0; mi < 4; mi++)
#pragma unroll
    for (int ni = 0; ni < 2; ni++)
#pragma unroll
      for (int r = 0; r < 4; r++) {
        int row = m0 + wr * 64 + mi * 16 + krow * 4 + r;
        int col = n0 + wc * 32 + ni * 16 + l16;
        float v = acc[mi][ni][r];
        if (OUTBF) ((unsigned short*)C)[(size_t)row * N + col] = f2bf(v);
        else       ((float*)C)[(size_t)row * N + col] = v;
      }
}

// ---------- V transpose (tiled): Vt[h*64+d][s] = QKV[s][2048 + h*64 + d] ----------
__global__ __launch_bounds__(256)
void k_vt(const unsigned short* __restrict__ QKV, unsigned short* __restrict__ Vt) {
  __shared__ unsigned short t[64 * 65];
  const int tid = threadIdx.x;
  const int s0 = blockIdx.x * 64, c0 = blockIdx.y * 64;
  const int sl = tid >> 3, ch = tid & 7;  // 32 rows x 8 chunks per pass
#pragma unroll
  for (int half = 0; half < 2; half++) {
    int s = half * 32 + sl;
    bf16x8 v = *(const bf16x8*)&QKV[(size_t)(s0 + s) * 3072 + 2048 + c0 + ch * 8];
#pragma unroll
    for (int k = 0; k < 8; k++) t[s * 65 + ch * 8 + k] = (unsigned short)v[k];
  }
  __syncthreads();
  const int cl = tid >> 2, si = (tid & 3) * 16;
  bf16x8 o0, o1;
#pragma unroll
  for (int i = 0; i < 8; i++) o0[i] = (short)t[(si + i) * 65 + cl];
#pragma unroll
  for (int i = 0; i < 8; i++) o1[i] = (short)t[(si + 8 + i) * 65 + cl];
  *(bf16x8*)&Vt[(size_t)(c0 + cl) * 4096 + s0 + si] = o0;
  *(bf16x8*)&Vt[(size_t)(c0 + cl) * 4096 + s0 + si + 8] = o1;
}

// ---------- flash attention ----------
// 8 waves/WG (512 thr), 128 q-rows/WG, 16 q-rows/wave, grid 512 (16 heads x 32 qb).
// LDS 32 KB dbuf K+V -> 2 WG/CU = 16 waves/CU with HALF of R9's staging traffic
// (each tile staged once per 128 q-rows instead of per 64). Swapped QK^T ->
// lane-local softmax (per-lane partial max, defer-max; per-lane partial l reduced
// in epilogue). PV: P^T B-frag = lane's own packed sacc under k-slot perm pi;
// V A-frag = two ds_read_b64 under the same pi.
__global__ __launch_bounds__(512)
void k_flash(const unsigned short* __restrict__ QKV, const unsigned short* __restrict__ Vt,
             unsigned short* __restrict__ ctx) {
  // shorts: dbuf 2 x (K 4096 | V 4096) = 32 KB
  __shared__ __align__(16) unsigned short LDS[16384];
  const int tid = threadIdx.x, wid = tid >> 6, lane = tid & 63;
  const int l16 = lane & 15, krow = lane >> 4;
  const int bid = blockIdx.x;
  const int swz = (bid & 7) * 64 + (bid >> 3);    // 512 % 8 == 0 -> bijective
  const int head = swz >> 5, qb = swz & 31;       // 2 heads per XCD (K/V/Q ~3MB < 4MB L2)
  const float SC = 0.125f * 1.44269504089f;       // scale into log2 domain

  // Q fragments (B-operand of swapped QK^T): lane holds q-row l16, d = ks*32+krow*8..+7
  bf16x8 qf[2];
#pragma unroll
  for (int ks = 0; ks < 2; ks++) {
    int row = qb * 128 + wid * 16 + l16;
    qf[ks] = *(const bf16x8*)&QKV[(size_t)row * 3072 + head * 64 + ks * 32 + krow * 8];
  }

  f32x4 oaccT[4] = {};      // O^T tiles [di]; col=q(l16), row=d(krow*4+r)
  float mrun = -INFINITY;   // uniform across the 4 krow-lanes of a q
  float lrun = 0.f;         // PER-LANE partial (reduced in epilogue)

  // one pass stages the whole 16 KB tile: 512 thr x (16B K + 16B V)
  auto stage = [&](int buf, int kt) {
    int row = tid >> 3, ch = tid & 7, sch = ch ^ (row & 7);  // pre-swizzled source
    gload_lds16(QKV + (size_t)(kt * 64 + row) * 3072 + 1024 + head * 64 + sch * 8,
                (char*)LDS + buf * 16384 + wid * 1024);          // + lane*16 by HW
    gload_lds16(Vt + (size_t)(head * 64 + row) * 4096 + kt * 64 + sch * 8,
                (char*)LDS + buf * 16384 + 8192 + wid * 1024);   // + lane*16 by HW
  };

  auto body = [&](int buf) {
    const unsigned short* Ks = LDS + buf * 8192;
    const char* VsB = (const char*)(LDS + buf * 8192 + 4096);

    // swapped QK^T: sacc[ni] = S^T tile [kv 16][q 16]; lane owns q=l16, kv=ni*16+krow*4+r
    f32x4 sacc[4] = {};
    __builtin_amdgcn_s_setprio(1);
#pragma unroll
    for (int ks = 0; ks < 2; ks++)
#pragma unroll
      for (int ni = 0; ni < 4; ni++) {
        int row = ni * 16 + l16;
        bf16x8 kf = *(const bf16x8*)&Ks[row * 64 + (((ks * 4 + krow) ^ (row & 7)) << 3)];
        sacc[ni] = __builtin_amdgcn_mfma_f32_16x16x32_bf16(kf, qf[ks], sacc[ni], 0, 0, 0);
      }
    __builtin_amdgcn_s_setprio(0);

    // per-lane partial max over this lane's 16 kv values (raw domain)
    float a = fmax3(sacc[0][0], sacc[0][1], sacc[0][2]);
    a = fmax3(a, sacc[0][3], sacc[1][0]);
    a = fmax3(a, sacc[1][1], sacc[1][2]);
    a = fmax3(a, sacc[1][3], sacc[2][0]);
    a = fmax3(a, sacc[2][1], sacc[2][2]);
    a = fmax3(a, sacc[2][3], sacc[3][0]);
    a = fmax3(a, sacc[3][1], sacc[3][2]);
    a = fmaxf(a, sacc[3][3]);

    // defer-max: cross-lane reduce + rescale only when some lane's partial
    // exceeds the running max by > 8 (log2 domain)
    if (__ballot(__builtin_fmaf(a, SC, -mrun) > 8.f)) {
      a = fmaxf(a, __shfl_xor(a, 16));
      a = fmaxf(a, __shfl_xor(a, 32));      // uniform per q now
      float mnew = fmaxf(mrun, a * SC);
      float al = __builtin_amdgcn_exp2f(mrun - mnew);
      lrun *= al;
      mrun = mnew;
#pragma unroll
      for (int di = 0; di < 4; di++)
#pragma unroll
        for (int r = 0; r < 4; r++) oaccT[di][r] *= al;
    }

    // P = exp2(s*SC - m); per-lane partial row-sum
#pragma unroll
    for (int ni = 0; ni < 4; ni++)
#pragma unroll
      for (int r = 0; r < 4; r++) {
        float p = __builtin_amdgcn_exp2f(__builtin_fmaf(sacc[ni][r], SC, -mrun));
        sacc[ni][r] = p;
        lrun += p;
      }

    // B-frags: P^T packed from this lane's OWN sacc under k-slot perm pi:
    //   pi(ks,krow,j) = (2ks + (j>>2))*16 + krow*4 + (j&3)
    union PB { unsigned int w[4]; bf16x8 v; };
    PB pb[2];
#pragma unroll
    for (int ks = 0; ks < 2; ks++) {
      pb[ks].w[0] = pack_trunc(sacc[2 * ks][0],     sacc[2 * ks][1]);
      pb[ks].w[1] = pack_trunc(sacc[2 * ks][2],     sacc[2 * ks][3]);
      pb[ks].w[2] = pack_trunc(sacc[2 * ks + 1][0], sacc[2 * ks + 1][1]);
      pb[ks].w[3] = pack_trunc(sacc[2 * ks + 1][2], sacc[2 * ks + 1][3]);
    }

    // O^T += V^T P^T: A-frag under same pi = two b64 reads from swizzled Vs
    __builtin_amdgcn_s_setprio(1);
#pragma unroll
    for (int ks = 0; ks < 2; ks++)
#pragma unroll
      for (int di = 0; di < 4; di++) {
        int row = di * 16 + l16;
        int base = row * 128 + ((krow & 1) << 3);
        union PB av;
        *(uint2*)&av.w[0] = *(const uint2*)(VsB + base + (((ks * 4 + (krow >> 1)) ^ (row & 7)) << 4));
        *(uint2*)&av.w[2] = *(const uint2*)(VsB + base + (((ks * 4 + 2 + (krow >> 1)) ^ (row & 7)) << 4));
        oaccT[di] = __builtin_amdgcn_mfma_f32_16x16x32_bf16(av.v, pb[ks].v, oaccT[di], 0, 0, 0);
      }
    __builtin_amdgcn_s_setprio(0);
  };

  stage(0, 0);
  __syncthreads();
  for (int kt = 0; kt < 64; kt += 2) {
    stage(1, kt + 1);
    body(0);
    __syncthreads();           // buf1 staged+drained; all reads of buf0 done
    if (kt + 2 < 64) stage(0, kt + 2);
    body(1);
    __syncthreads();
  }

  // epilogue: reduce per-lane l partials across the 4 krow-lanes of each q,
  // then per-lane normalize + 8B packed stores
  float lr = lrun;
  lr += __shfl_xor(lr, 16);
  lr += __shfl_xor(lr, 32);
  float li = 1.0f / lr;
  int row = qb * 128 + wid * 16 + l16;
#pragma unroll
  for (int di = 0; di < 4; di++) {
    uint2 w;
    w.x = (unsigned)f2bf(oaccT[di][0] * li) | ((unsigned)f2bf(oaccT[di][1] * li) << 16);
    w.y = (unsigned)f2bf(oaccT[di][2] * li) | ((unsigned)f2bf(oaccT[di][3] * li) << 16);
    *(uint2*)&ctx[(size_t)row * 1024 + head * 64 + di * 16 + krow * 4] = w;
  }
}

// ---------- LN(base + add): emits fp32 + bf16 copies ----------
__global__ __launch_bounds__(256)
void k_ln_res(const float* __restrict__ base, const float* __restrict__ add,
              const float* __restrict__ g, const float* __restrict__ bb,
              float* __restrict__ outf, unsigned short* __restrict__ outb) {
  const int r = blockIdx.x, tid = threadIdx.x;
  float4 v = ((const float4*)(base + (size_t)r * 1024))[tid];
  {
    float4 w = ((const float4*)(add + (size_t)r * 1024))[tid];
    v.x += w.x; v.y += w.y; v.z += w.z; v.w += w.w;
  }
  float s1 = v.x + v.y + v.z + v.w;
  float s2 = v.x * v.x + v.y * v.y + v.z * v.z + v.w * v.w;
#pragma unroll
  for (int off = 32; off >= 1; off >>= 1) { s1 += __shfl_xor(s1, off); s2 += __shfl_xor(s2, off); }
  __shared__ float red[8];
  if ((tid & 63) == 0) { red[tid >> 6] = s1; red[4 + (tid >> 6)] = s2; }
  __syncthreads();
  s1 = red[0] + red[1] + red[2] + red[3];
  s2 = red[4] + red[5] + red[6] + red[7];
  const float mu = s1 * (1.0f / 1024.0f);
  const float var = s2 * (1.0f / 1024.0f) - mu * mu;
  const float rs = rsqrtf(var + 1e-5f);
  float4 gv = ((const float4*)g)[tid];
  float4 bv = ((const float4*)bb)[tid];
  float4 y;
  y.x = (v.x - mu) * rs * gv.x + bv.x;
  y.y = (v.y - mu) * rs * gv.y + bv.y;
  y.z = (v.z - mu) * rs * gv.z + bv.z;
  y.w = (v.w - mu) * rs * gv.w + bv.w;
  ((float4*)(outf + (size_t)r * 1024))[tid] = y;
  u16x4 o;
  o.x = f2bf(y.x); o.y = f2bf(y.y); o.z = f2bf(y.z); o.w = f2bf(y.w);
  ((u16x4*)(outb + (size_t)r * 1024))[tid] = o;
}

// ---------- relu(LN(lin + out_b + mha)) -> fp32 out ----------
__global__ __launch_bounds__(256)
void k_ln2(const float* __restrict__ lin, const float* __restrict__ mha,
           const float* __restrict__ ob, const float* __restrict__ g,
           const float* __restrict__ bb, float* __restrict__ out) {
  const int r = blockIdx.x, tid = threadIdx.x;
  float4 v = ((const float4*)(lin + (size_t)r * 1024))[tid];
  {
    float4 w = ((const float4*)(mha + (size_t)r * 1024))[tid];
    float4 o = ((const float4*)ob)[tid];
    v.x += w.x + o.x; v.y += w.y + o.y; v.z += w.z + o.z; v.w += w.w + o.w;
  }
  float s1 = v.x + v.y + v.z + v.w;
  float s2 = v.x * v.x + v.y * v.y + v.z * v.z + v.w * v.w;
#pragma unroll
  for (int off = 32; off >= 1; off >>= 1) { s1 += __shfl_xor(s1, off); s2 += __shfl_xor(s2, off); }
  __shared__ float red[8];
  if ((tid & 63) == 0) { red[tid >> 6] = s1; red[4 + (tid >> 6)] = s2; }
  __syncthreads();
  s1 = red[0] + red[1] + red[2] + red[3];
  s2 = red[4] + red[5] + red[6] + red[7];
  const float mu = s1 * (1.0f / 1024.0f);
  const float var = s2 * (1.0f / 1024.0f) - mu * mu;
  const float rs = rsqrtf(var + 1e-5f);
  float4 gv = ((const float4*)g)[tid];
  float4 bv = ((const float4*)bb)[tid];
  float4 y;
  y.x = fmaxf(0.f, (v.x - mu) * rs * gv.x + bv.x);
  y.y = fmaxf(0.f, (v.y - mu) * rs * gv.y + bv.y);
  y.z = fmaxf(0.f, (v.z - mu) * rs * gv.z + bv.z);
  y.w = fmaxf(0.f, (v.w - mu) * rs * gv.w + bv.w);
  ((float4*)(out + (size_t)r * 1024))[tid] = y;
}

// ---------- launch ----------
extern "C" void kernel_launch(void* const* d_in, const int* in_sizes, int n_in,
                              void* d_out, int out_size, void* d_ws, size_t ws_size,
                              hipStream_t stream) {
  (void)in_sizes; (void)n_in; (void)out_size; (void)ws_size;
  const float* x     = (const float*)d_in[0];
  const float* Wq    = (const float*)d_in[1];
  const float* Wk    = (const float*)d_in[2];
  const float* Wv    = (const float*)d_in[3];
  const float* Wo    = (const float*)d_in[4];
  const float* out_w = (const float*)d_in[5];
  const float* out_b = (const float*)d_in[6];
  const float* g1    = (const float*)d_in[7];
  const float* b1    = (const float*)d_in[8];
  const float* g2    = (const float*)d_in[9];
  const float* b2    = (const float*)d_in[10];
  float* out = (float*)d_out;

  // workspace layout (aliased; 60 MB total, liveness-checked)
  const size_t MB = 1ull << 20;
  char* ws = (char*)d_ws;
  unsigned short* xb    = (unsigned short*)(ws + 0);        // [4096][1024] bf16   (dead after GEMM1)
  unsigned short* WqkvT = (unsigned short*)(ws + 8 * MB);   // [3072][1024] bf16   (dead after GEMM1)
  unsigned short* OwB   = (unsigned short*)(ws + 16 * MB);  // out_w bf16 [1024][1024]
  unsigned short* QKV   = (unsigned short*)(ws + 18 * MB);  // [4096][3072] bf16   (dead after attn)
  unsigned short* Vt    = (unsigned short*)(ws + 42 * MB);  // [1024][4096] bf16   (dead after attn)
  unsigned short* ctx   = (unsigned short*)(ws + 50 * MB);  // [4096][1024] bf16   (dead after GEMM2)
  unsigned short* WoT   = (unsigned short*)(ws + 58 * MB);  // W_o^T bf16
  float*          proj  = (float*)(ws + 0);                 // [4096][1024] f32 (over xb/WqkvT)
  float*          mhaF  = (float*)(ws + 18 * MB);           // [4096][1024] f32 (over QKV head)
  unsigned short* mhaB  = (unsigned short*)(ws + 34 * MB);  // [4096][1024] bf16 (over QKV tail)
  float*          lin   = (float*)(ws + 42 * MB);           // [4096][1024] f32 (over Vt/ctx)

  k_convert2<<<5120, 256, 0, stream>>>(x, xb, out_w, OwB, 1048576, 262144);
  k_transpose4<<<dim3(32, 32, 4), 256, 0, stream>>>(Wq, Wk, Wv, Wo, WqkvT, WoT);

  k_gemm_bt<1><<<dim3(32, 24), 256, 0, stream>>>(xb, WqkvT, QKV, 4096, 3072, 1024);
  k_vt<<<dim3(64, 16), 256, 0, stream>>>(QKV, Vt);
  k_flash<<<512, 512, 0, stream>>>(QKV, Vt, ctx);
  k_gemm_bt_n64<0><<<dim3(32, 16), 256, 0, stream>>>(ctx, WoT, proj, 4096, 1024, 1024);
  k_ln_res<<<4096, 256, 0, stream>>>(x, proj, g1, b1, mhaF, mhaB);
  k_gemm_bt_n64<0><<<dim3(32, 16), 256, 0, stream>>>(mhaB, OwB, lin, 4096, 1024, 1024);
  k_ln2<<<4096, 256, 0, stream>>>(lin, mhaF, out_b, g2, b2, out);
}